// Round 2
// baseline (163.833 us; speedup 1.0000x reference)
//
#include <hip/hip_runtime.h>
#include <math.h>

// Net_90434831385322: z = A + span*sigmoid(relu((x-A)/span @ W1 + b1) @ W2 + b2)
// BATCH=4194304, OBS=4, HID=64, ACT=4, all fp32.
//
// R1: weights live in SGPRs (uniform s_load from prefolded ws), not LDS.
//     __launch_bounds__(256,4) -> 128 VGPR budget so xr[8]+acc[8] (64 VGPRs)
//     fit without AGPR/scratch spill shuffles (R0: VGPR=52 + spill moves was
//     the 1.8x VALU inflation). No __shared__, no barriers in the hot kernel.

#define BATCH   4194304
#define HID     64
#define ROWS    8
#define TPB     256
#define NBLK    (BATCH / (TPB * ROWS))   // 2048 blocks = 8 blocks/CU = 2 passes at 4/CU

// ws layout (floats):
//   [0   .. 255]  W1' grouped per j: {W1'[0][j], W1'[1][j], W1'[2][j], W1'[3][j]}
//   [256 .. 511]  W2  grouped per j: {W2[j][0..3]}
//   [512 .. 575]  b1'[j]
//   [576 .. 579]  b2[0..3]
#define WS_FLOATS 580

__global__ __launch_bounds__(64)
void prep_kernel(const float* __restrict__ W1, const float* __restrict__ b1,
                 const float* __restrict__ W2, const float* __restrict__ b2,
                 float* __restrict__ ws) {
    const float A[4] = {0.001f, 0.02f, 0.05f, 0.001f};
    const float S[4] = {0.003f, 0.03f, 0.15f, 0.003f};  // span = B - A
    int j = threadIdx.x;           // 0..63
    if (j < HID) {
        float bb = b1[j];
        #pragma unroll
        for (int k = 0; k < 4; ++k) {
            float wv = W1[k * HID + j];
            ws[j * 4 + k] = wv / S[k];          // fold input scaling into W1
            bb -= (A[k] / S[k]) * wv;           // and into b1
        }
        ws[512 + j] = bb;
        #pragma unroll
        for (int i = 0; i < 4; ++i)
            ws[256 + j * 4 + i] = W2[j * 4 + i];
    }
    if (j < 4) ws[576 + j] = b2[j];
}

__global__ __launch_bounds__(TPB, 4)
void mlp_kernel(const float* __restrict__ x, const float* __restrict__ ws,
                float* __restrict__ out) {
    const long base = (long)blockIdx.x * (TPB * ROWS) + threadIdx.x;
    const float4* __restrict__ x4   = (const float4*)x;
    float4* __restrict__       out4 = (float4*)out;

    // 8 rows up front: coalesced global_load_dwordx4, latency overlapped
    // with the (scalar-cached) weight loads below.
    float4 xr[ROWS];
    #pragma unroll
    for (int r = 0; r < ROWS; ++r) xr[r] = x4[base + (long)r * TPB];

    // b2 broadcast: uniform address -> s_load, stays in SGPRs
    const float b2x = ws[576], b2y = ws[577], b2z = ws[578], b2w = ws[579];
    float4 acc[ROWS];
    #pragma unroll
    for (int r = 0; r < ROWS; ++r) acc[r] = make_float4(b2x, b2y, b2z, b2w);

    // Hidden loop, fully unrolled. All ws[...] indices are compile-time
    // constants off a uniform pointer -> s_load_dwordx16 batches; each
    // v_fma reads one SGPR weight operand (legal: 1 SGPR/VALU instr).
    #pragma unroll
    for (int j = 0; j < HID; ++j) {
        const float w1x = ws[j * 4 + 0];
        const float w1y = ws[j * 4 + 1];
        const float w1z = ws[j * 4 + 2];
        const float w1w = ws[j * 4 + 3];
        const float w2x = ws[256 + j * 4 + 0];
        const float w2y = ws[256 + j * 4 + 1];
        const float w2z = ws[256 + j * 4 + 2];
        const float w2w = ws[256 + j * 4 + 3];
        const float b   = ws[512 + j];
        #pragma unroll
        for (int r = 0; r < ROWS; ++r) {
            float t = fmaf(xr[r].x, w1x, b);
            t = fmaf(xr[r].y, w1y, t);
            t = fmaf(xr[r].z, w1z, t);
            t = fmaf(xr[r].w, w1w, t);
            t = fmaxf(t, 0.0f);
            acc[r].x = fmaf(t, w2x, acc[r].x);
            acc[r].y = fmaf(t, w2y, acc[r].y);
            acc[r].z = fmaf(t, w2z, acc[r].z);
            acc[r].w = fmaf(t, w2w, acc[r].w);
        }
    }

    // z = A + span * sigmoid(y):  r = 1/(1+exp(-y)); z = fma(span, r, A)
    const float A0 = 0.001f, A1 = 0.02f, A2 = 0.05f, A3 = 0.001f;
    const float S0 = 0.003f, S1 = 0.03f, S2 = 0.15f, S3 = 0.003f;
    #pragma unroll
    for (int r = 0; r < ROWS; ++r) {
        float4 z;
        z.x = fmaf(S0, 1.0f / (1.0f + __expf(-acc[r].x)), A0);
        z.y = fmaf(S1, 1.0f / (1.0f + __expf(-acc[r].y)), A1);
        z.z = fmaf(S2, 1.0f / (1.0f + __expf(-acc[r].z)), A2);
        z.w = fmaf(S3, 1.0f / (1.0f + __expf(-acc[r].w)), A3);
        out4[base + (long)r * TPB] = z;
    }
}

extern "C" void kernel_launch(void* const* d_in, const int* in_sizes, int n_in,
                              void* d_out, int out_size, void* d_ws, size_t ws_size,
                              hipStream_t stream) {
    const float* x  = (const float*)d_in[0];
    const float* W1 = (const float*)d_in[1];
    const float* b1 = (const float*)d_in[2];
    const float* W2 = (const float*)d_in[3];
    const float* b2 = (const float*)d_in[4];
    float* out = (float*)d_out;
    float* ws  = (float*)d_ws;

    prep_kernel<<<1, 64, 0, stream>>>(W1, b1, W2, b2, ws);
    mlp_kernel<<<NBLK, TPB, 0, stream>>>(x, ws, out);
}

// Round 3
// 160.795 us; speedup vs baseline: 1.0189x; 1.0189x over previous
//
#include <hip/hip_runtime.h>
#include <math.h>

// Net_90434831385322: z = A + span*sigmoid(relu((x-A)/span @ W1 + b1) @ W2 + b2)
// BATCH=4194304, OBS=4, HID=64, ACT=4, all fp32.
//
// R2: ROWS=4 (small live set: xr[4]+acc[4]=32 VGPR) + LDS-broadcast weights
//     (v_fma(v,v,v) encodable; R1's SGPR weights forced v_mov per j) +
//     launch_bounds(256,6) with ~30 VGPR slack so the allocator does NOT
//     squeeze arch-VGPRs and shuffle state through AGPRs (R0/R1: VGPR 52/36
//     << natural live set; back-computed VALU issue was 2x the hand count —
//     AGPR copies / rematerialization is the suspected inflation).

#define BATCH   4194304
#define HID     64
#define ROWS    4
#define TPB     256
#define NBLK    (BATCH / (TPB * ROWS))   // 4096 blocks = 16 blocks/CU

// ws layout (floats):
//   [0   .. 255]  W1' grouped per j: {W1'[0][j], W1'[1][j], W1'[2][j], W1'[3][j]}
//   [256 .. 511]  W2  grouped per j: {W2[j][0..3]}
//   [512 .. 575]  b1'[j]
//   [576 .. 579]  b2[0..3]
#define WS_FLOATS 580

__global__ __launch_bounds__(64)
void prep_kernel(const float* __restrict__ W1, const float* __restrict__ b1,
                 const float* __restrict__ W2, const float* __restrict__ b2,
                 float* __restrict__ ws) {
    const float A[4] = {0.001f, 0.02f, 0.05f, 0.001f};
    const float S[4] = {0.003f, 0.03f, 0.15f, 0.003f};  // span = B - A
    int j = threadIdx.x;           // 0..63
    if (j < HID) {
        float bb = b1[j];
        #pragma unroll
        for (int k = 0; k < 4; ++k) {
            float wv = W1[k * HID + j];
            ws[j * 4 + k] = wv / S[k];          // fold input scaling into W1
            bb -= (A[k] / S[k]) * wv;           // and into b1
        }
        ws[512 + j] = bb;
        #pragma unroll
        for (int i = 0; i < 4; ++i)
            ws[256 + j * 4 + i] = W2[j * 4 + i];
    }
    if (j < 4) ws[576 + j] = b2[j];
}

__global__ __launch_bounds__(TPB, 6)
void mlp_kernel(const float* __restrict__ x, const float* __restrict__ ws,
                float* __restrict__ out) {
    __shared__ __align__(16) float s[WS_FLOATS];
    #pragma unroll
    for (int i = threadIdx.x; i < WS_FLOATS; i += TPB) s[i] = ws[i];
    __syncthreads();

    const float4* sW1 = (const float4*)(s);         // 16B-aligned
    const float4* sW2 = (const float4*)(s + 256);
    const float*  sB1 = s + 512;
    const float*  sB2 = s + 576;

    const long base = (long)blockIdx.x * (TPB * ROWS) + threadIdx.x;
    const float4* __restrict__ x4   = (const float4*)x;
    float4* __restrict__       out4 = (float4*)out;

    // 4 rows per thread, coalesced dwordx4 loads.
    float4 xr0 = x4[base];
    float4 xr1 = x4[base + TPB];
    float4 xr2 = x4[base + 2 * TPB];
    float4 xr3 = x4[base + 3 * TPB];

    const float b2x = sB2[0], b2y = sB2[1], b2z = sB2[2], b2w = sB2[3];
    float4 a0 = make_float4(b2x, b2y, b2z, b2w);
    float4 a1 = a0, a2 = a0, a3 = a0;

    // 3 LDS broadcast reads per j amortized over 4 rows; 36 VALU per j.
    #pragma unroll 8
    for (int j = 0; j < HID; ++j) {
        const float4 w1 = sW1[j];
        const float4 w2 = sW2[j];
        const float  b  = sB1[j];

        float t0 = fmaf(xr0.x, w1.x, b);
        t0 = fmaf(xr0.y, w1.y, t0);
        t0 = fmaf(xr0.z, w1.z, t0);
        t0 = fmaf(xr0.w, w1.w, t0);
        t0 = fmaxf(t0, 0.0f);
        a0.x = fmaf(t0, w2.x, a0.x);
        a0.y = fmaf(t0, w2.y, a0.y);
        a0.z = fmaf(t0, w2.z, a0.z);
        a0.w = fmaf(t0, w2.w, a0.w);

        float t1 = fmaf(xr1.x, w1.x, b);
        t1 = fmaf(xr1.y, w1.y, t1);
        t1 = fmaf(xr1.z, w1.z, t1);
        t1 = fmaf(xr1.w, w1.w, t1);
        t1 = fmaxf(t1, 0.0f);
        a1.x = fmaf(t1, w2.x, a1.x);
        a1.y = fmaf(t1, w2.y, a1.y);
        a1.z = fmaf(t1, w2.z, a1.z);
        a1.w = fmaf(t1, w2.w, a1.w);

        float t2 = fmaf(xr2.x, w1.x, b);
        t2 = fmaf(xr2.y, w1.y, t2);
        t2 = fmaf(xr2.z, w1.z, t2);
        t2 = fmaf(xr2.w, w1.w, t2);
        t2 = fmaxf(t2, 0.0f);
        a2.x = fmaf(t2, w2.x, a2.x);
        a2.y = fmaf(t2, w2.y, a2.y);
        a2.z = fmaf(t2, w2.z, a2.z);
        a2.w = fmaf(t2, w2.w, a2.w);

        float t3 = fmaf(xr3.x, w1.x, b);
        t3 = fmaf(xr3.y, w1.y, t3);
        t3 = fmaf(xr3.z, w1.z, t3);
        t3 = fmaf(xr3.w, w1.w, t3);
        t3 = fmaxf(t3, 0.0f);
        a3.x = fmaf(t3, w2.x, a3.x);
        a3.y = fmaf(t3, w2.y, a3.y);
        a3.z = fmaf(t3, w2.z, a3.z);
        a3.w = fmaf(t3, w2.w, a3.w);
    }

    // z = A + span * sigmoid(y):  z = fma(span, 1/(1+exp(-y)), A)
    const float A0 = 0.001f, A1 = 0.02f, A2 = 0.05f, A3 = 0.001f;
    const float S0 = 0.003f, S1 = 0.03f, S2 = 0.15f, S3 = 0.003f;
    float4 z;
    z.x = fmaf(S0, 1.0f / (1.0f + __expf(-a0.x)), A0);
    z.y = fmaf(S1, 1.0f / (1.0f + __expf(-a0.y)), A1);
    z.z = fmaf(S2, 1.0f / (1.0f + __expf(-a0.z)), A2);
    z.w = fmaf(S3, 1.0f / (1.0f + __expf(-a0.w)), A3);
    out4[base] = z;
    z.x = fmaf(S0, 1.0f / (1.0f + __expf(-a1.x)), A0);
    z.y = fmaf(S1, 1.0f / (1.0f + __expf(-a1.y)), A1);
    z.z = fmaf(S2, 1.0f / (1.0f + __expf(-a1.z)), A2);
    z.w = fmaf(S3, 1.0f / (1.0f + __expf(-a1.w)), A3);
    out4[base + TPB] = z;
    z.x = fmaf(S0, 1.0f / (1.0f + __expf(-a2.x)), A0);
    z.y = fmaf(S1, 1.0f / (1.0f + __expf(-a2.y)), A1);
    z.z = fmaf(S2, 1.0f / (1.0f + __expf(-a2.z)), A2);
    z.w = fmaf(S3, 1.0f / (1.0f + __expf(-a2.w)), A3);
    out4[base + 2 * TPB] = z;
    z.x = fmaf(S0, 1.0f / (1.0f + __expf(-a3.x)), A0);
    z.y = fmaf(S1, 1.0f / (1.0f + __expf(-a3.y)), A1);
    z.z = fmaf(S2, 1.0f / (1.0f + __expf(-a3.z)), A2);
    z.w = fmaf(S3, 1.0f / (1.0f + __expf(-a3.w)), A3);
    out4[base + 3 * TPB] = z;
}

extern "C" void kernel_launch(void* const* d_in, const int* in_sizes, int n_in,
                              void* d_out, int out_size, void* d_ws, size_t ws_size,
                              hipStream_t stream) {
    const float* x  = (const float*)d_in[0];
    const float* W1 = (const float*)d_in[1];
    const float* b1 = (const float*)d_in[2];
    const float* W2 = (const float*)d_in[3];
    const float* b2 = (const float*)d_in[4];
    float* out = (float*)d_out;
    float* ws  = (float*)d_ws;

    prep_kernel<<<1, 64, 0, stream>>>(W1, b1, W2, b2, ws);
    mlp_kernel<<<NBLK, TPB, 0, stream>>>(x, ws, out);
}

// Round 4
// 151.101 us; speedup vs baseline: 1.0843x; 1.0642x over previous
//
#include <hip/hip_runtime.h>
#include <math.h>

// Net_90434831385322: z = A + span*sigmoid(relu((x-A)/span @ W1 + b1) @ W2 + b2)
// BATCH=4194304, OBS=4, HID=64, ACT=4, all fp32.
//
// R3: packed fp32 (v_pk_fma_f32 via float2 ext-vectors). Two batch rows per
//     lane-register-pair -> 9 packed ops per j per row-pair vs 18 scalar.
//     Weights DUPLICATED in LDS ({w,w} pairs) so packed operands are plain
//     VGPR pairs (no per-j replication movs). R0-R2 all issue ~same scalar
//     instr count and all land 68-77us = ~64% of the empirical ~103 TF fp32
//     ceiling (m07); instruction ISSUE is the binding resource -> halve it.

#define BATCH   4194304
#define HID     64
#define ROWS    8                         // 4 packed pairs per thread
#define TPB     256
#define NBLK    (BATCH / (TPB * ROWS))    // 2048 blocks

// ws layout (floats): per j (20-float block, 80B, 16B-aligned):
//   [j*20 + 0.. 7]  w1 duplicated: {w1x,w1x,w1y,w1y,w1z,w1z,w1w,w1w}  (input-scale folded)
//   [j*20 + 8..15]  w2 duplicated: {w2x,w2x,w2y,w2y,w2z,w2z,w2w,w2w}
//   [j*20 +16..17]  {b1'j, b1'j}
//   [j*20 +18..19]  pad
//   [1280..1283]    b2[0..3]
#define WS_FLOATS 1284

typedef float v2f __attribute__((ext_vector_type(2)));
typedef float v4f __attribute__((ext_vector_type(4)));

#if __has_builtin(__builtin_elementwise_fma)
#define VFMA(a, b, c) __builtin_elementwise_fma((a), (b), (c))
#else
#define VFMA(a, b, c) ((a) * (b) + (c))
#endif

static __device__ __forceinline__ v2f vmax0(v2f t) {
#if __has_builtin(__builtin_elementwise_max)
    v2f z = {0.0f, 0.0f};
    return __builtin_elementwise_max(t, z);
#else
    v2f r;
    r.x = fmaxf(t.x, 0.0f);
    r.y = fmaxf(t.y, 0.0f);
    return r;
#endif
}

__global__ __launch_bounds__(64)
void prep_kernel(const float* __restrict__ W1, const float* __restrict__ b1,
                 const float* __restrict__ W2, const float* __restrict__ b2,
                 float* __restrict__ ws) {
    const float A[4] = {0.001f, 0.02f, 0.05f, 0.001f};
    const float S[4] = {0.003f, 0.03f, 0.15f, 0.003f};  // span = B - A
    int j = threadIdx.x;  // 0..63
    if (j < HID) {
        float bb = b1[j];
        #pragma unroll
        for (int k = 0; k < 4; ++k) {
            float wv = W1[k * HID + j];
            float wd = wv / S[k];               // fold input scaling into W1
            bb -= (A[k] / S[k]) * wv;           // and into b1
            ws[j * 20 + 2 * k]     = wd;
            ws[j * 20 + 2 * k + 1] = wd;
        }
        #pragma unroll
        for (int i = 0; i < 4; ++i) {
            float wv = W2[j * 4 + i];
            ws[j * 20 + 8 + 2 * i]     = wv;
            ws[j * 20 + 8 + 2 * i + 1] = wv;
        }
        ws[j * 20 + 16] = bb;
        ws[j * 20 + 17] = bb;
        ws[j * 20 + 18] = 0.0f;
        ws[j * 20 + 19] = 0.0f;
    }
    if (j < 4) ws[1280 + j] = b2[j];
}

__global__ __launch_bounds__(TPB, 4)
void mlp_kernel(const float* __restrict__ x, const float* __restrict__ ws,
                float* __restrict__ out) {
    __shared__ __align__(16) float s[WS_FLOATS];
    for (int i = threadIdx.x; i < WS_FLOATS; i += TPB) s[i] = ws[i];
    __syncthreads();

    const long base = (long)blockIdx.x * (TPB * ROWS) + threadIdx.x;
    const v4f* __restrict__ x4   = (const v4f*)x;
    v4f* __restrict__       out4 = (v4f*)out;

    // 8 rows, coalesced dwordx4 loads.
    v4f xr[ROWS];
    #pragma unroll
    for (int r = 0; r < ROWS; ++r) xr[r] = x4[base + (long)r * TPB];

    // Pack rows (2p, 2p+1) element-wise into float2 pairs (one-time movs).
    v2f X[4][4];
    #pragma unroll
    for (int p = 0; p < 4; ++p)
        #pragma unroll
        for (int e = 0; e < 4; ++e) {
            v2f t = {xr[2 * p][e], xr[2 * p + 1][e]};
            X[p][e] = t;
        }

    // Acc: Ac[p][c] = {y_c(row 2p), y_c(row 2p+1)}, init b2[c].
    v2f Ac[4][4];
    #pragma unroll
    for (int p = 0; p < 4; ++p)
        #pragma unroll
        for (int c = 0; c < 4; ++c) {
            v2f t = {s[1280 + c], s[1280 + c]};
            Ac[p][c] = t;
        }

    const v4f* sw = (const v4f*)s;

    // Per j: 4x ds_read_b128 + 1x b64 (broadcast, conflict-free), then
    // 4 pairs x 9 v_pk_fma/pk_max = 37 packed VALU for 8 rows.
    #pragma unroll 4
    for (int j = 0; j < HID; ++j) {
        const v4f q0 = sw[j * 5 + 0];            // w1x w1x w1y w1y
        const v4f q1 = sw[j * 5 + 1];            // w1z w1z w1w w1w
        const v4f q2 = sw[j * 5 + 2];            // w2x w2x w2y w2y
        const v4f q3 = sw[j * 5 + 3];            // w2z w2z w2w w2w
        const v2f bb = *(const v2f*)(s + j * 20 + 16);
        #pragma unroll
        for (int p = 0; p < 4; ++p) {
            v2f t = VFMA(X[p][0], q0.xy, bb);
            t = VFMA(X[p][1], q0.zw, t);
            t = VFMA(X[p][2], q1.xy, t);
            t = VFMA(X[p][3], q1.zw, t);
            t = vmax0(t);
            Ac[p][0] = VFMA(t, q2.xy, Ac[p][0]);
            Ac[p][1] = VFMA(t, q2.zw, Ac[p][1]);
            Ac[p][2] = VFMA(t, q3.xy, Ac[p][2]);
            Ac[p][3] = VFMA(t, q3.zw, Ac[p][3]);
        }
    }

    // z = A + span * sigmoid(y):  z_c = fma(span_c, 1/(1+exp(-y_c)), A_c)
    const float LA[4] = {0.001f, 0.02f, 0.05f, 0.001f};
    const float LS[4] = {0.003f, 0.03f, 0.15f, 0.003f};
    #pragma unroll
    for (int p = 0; p < 4; ++p) {
        v4f z0, z1;
        #pragma unroll
        for (int c = 0; c < 4; ++c) {
            z0[c] = fmaf(LS[c], 1.0f / (1.0f + __expf(-Ac[p][c].x)), LA[c]);
            z1[c] = fmaf(LS[c], 1.0f / (1.0f + __expf(-Ac[p][c].y)), LA[c]);
        }
        out4[base + (long)(2 * p) * TPB]     = z0;
        out4[base + (long)(2 * p + 1) * TPB] = z1;
    }
}

extern "C" void kernel_launch(void* const* d_in, const int* in_sizes, int n_in,
                              void* d_out, int out_size, void* d_ws, size_t ws_size,
                              hipStream_t stream) {
    const float* x  = (const float*)d_in[0];
    const float* W1 = (const float*)d_in[1];
    const float* b1 = (const float*)d_in[2];
    const float* W2 = (const float*)d_in[3];
    const float* b2 = (const float*)d_in[4];
    float* out = (float*)d_out;
    float* ws  = (float*)d_ws;

    prep_kernel<<<1, 64, 0, stream>>>(W1, b1, W2, b2, ws);
    mlp_kernel<<<NBLK, TPB, 0, stream>>>(x, ws, out);
}